// Round 2
// baseline (424.298 us; speedup 1.0000x reference)
//
#include <hip/hip_runtime.h>

// CausalSelfAttention: B=4, T=2048, C=1024, H=16, d_k=64
// Pipeline: convert(x,W)->bf16  |  GEMM1 qkv (+scatter Q,K,Vt)  |  flash attn  |  GEMM2 out
#define T_SEQ 2048
#define NBATCH 4
#define NHEAD 16
#define DKH 64
#define CEMB 1024

typedef unsigned short u16;
typedef __attribute__((ext_vector_type(8))) short short8;
typedef __attribute__((ext_vector_type(8))) unsigned short ushort8v;
typedef __attribute__((ext_vector_type(4))) float f32x4;

__device__ __forceinline__ u16 f2bf(float f) {
  unsigned int x = __builtin_bit_cast(unsigned int, f);
  x += 0x7FFFu + ((x >> 16) & 1u);   // RNE
  return (u16)(x >> 16);
}

__device__ __forceinline__ void async_copy16(const void* g, void* lds) {
  __builtin_amdgcn_global_load_lds(
      (const __attribute__((address_space(1))) void*)g,
      (__attribute__((address_space(3))) void*)lds, 16, 0, 0);
}

// ---------------- convert f32 -> bf16 (8 elems/thread) ----------------
__global__ __launch_bounds__(256) void k_convert(const float* __restrict__ in,
                                                 u16* __restrict__ out, int n8) {
  int i = blockIdx.x * 256 + threadIdx.x;
  if (i >= n8) return;
  const float4* p = (const float4*)in;
  float4 a = p[2 * i], b = p[2 * i + 1];
  ushort8v v;
  v[0] = f2bf(a.x); v[1] = f2bf(a.y); v[2] = f2bf(a.z); v[3] = f2bf(a.w);
  v[4] = f2bf(b.x); v[5] = f2bf(b.y); v[6] = f2bf(b.z); v[7] = f2bf(b.w);
  ((ushort8v*)out)[i] = v;
}

// ---------------- transpose+convert: W[R][C] f32 -> WT[C][R] bf16 ----------------
__global__ __launch_bounds__(256) void k_transpose(const float* __restrict__ W,
                                                   u16* __restrict__ WT, int R, int C) {
  __shared__ float tile[32][33];
  int c0 = blockIdx.x * 32, r0 = blockIdx.y * 32;
  int tx = threadIdx.x & 31;
  int ty = threadIdx.x >> 5;  // 0..7
#pragma unroll
  for (int i = 0; i < 4; ++i) {
    int r = ty + i * 8;
    tile[r][tx] = W[(size_t)(r0 + r) * C + c0 + tx];
  }
  __syncthreads();
#pragma unroll
  for (int i = 0; i < 4; ++i) {
    int cc = ty + i * 8;
    WT[(size_t)(c0 + cc) * R + r0 + tx] = f2bf(tile[tx][cc]);
  }
}

// ---------------- GEMM C = A[M,K] * BT[N,K]^T  (bf16 in, f32 acc) ----------------
// m97 structure: 128x128 tile, BK=32, 4 waves (2x2 of 64x64), 4x4 frags, global_load_lds.
// EPI=0: Cf[M,N] = acc + bias[n]   (f32 out)
// EPI=1: scatter qkv: n<1024 -> Qb[B,H,T,64]; <2048 -> Kb; else Vtb[B,H,64,T] (transposed)
template <int EPI>
__global__ __launch_bounds__(256) void k_gemm_bt(
    const u16* __restrict__ A, const u16* __restrict__ BT, const float* __restrict__ bias,
    float* __restrict__ Cf, u16* __restrict__ Qb, u16* __restrict__ Kb, u16* __restrict__ Vtb,
    int M, int N, int K) {
  __shared__ u16 As[128 * 32];
  __shared__ u16 Bs[128 * 32];
  const int tid = threadIdx.x;
  const int w = tid >> 6, l = tid & 63;
  const int g = l >> 4, lr = l & 15;
  const int m0 = blockIdx.y * 128, n0 = blockIdx.x * 128;
  const int wr = (w >> 1) * 64, wc = (w & 1) * 64;
  f32x4 acc[4][4] = {};

  const int srow = l >> 2;           // 0..15
  const int scol = (l & 3) << 3;     // 0,8,16,24
  const u16* Ag = A + (size_t)m0 * K + scol;
  const u16* Bg = BT + (size_t)n0 * K + scol;

  for (int k0 = 0; k0 < K; k0 += 32) {
#pragma unroll
    for (int i = 0; i < 2; ++i) {
      int blk = i * 4 + w;           // 0..7: 16-row chunk of the tile
      int row = blk * 16 + srow;
      async_copy16(Ag + (size_t)row * K + k0, &As[blk * 512]);
      async_copy16(Bg + (size_t)row * K + k0, &Bs[blk * 512]);
    }
    __syncthreads();
    short8 af[4], bf[4];
#pragma unroll
    for (int mi = 0; mi < 4; ++mi)
      af[mi] = *(const short8*)&As[(wr + mi * 16 + lr) * 32 + g * 8];
#pragma unroll
    for (int ni = 0; ni < 4; ++ni)
      bf[ni] = *(const short8*)&Bs[(wc + ni * 16 + lr) * 32 + g * 8];
#pragma unroll
    for (int mi = 0; mi < 4; ++mi)
#pragma unroll
      for (int ni = 0; ni < 4; ++ni)
        acc[mi][ni] = __builtin_amdgcn_mfma_f32_16x16x32_bf16(af[mi], bf[ni], acc[mi][ni], 0, 0, 0);
    __syncthreads();
  }

  if constexpr (EPI == 0) {
#pragma unroll
    for (int mi = 0; mi < 4; ++mi) {
#pragma unroll
      for (int ni = 0; ni < 4; ++ni) {
        int ng = n0 + wc + ni * 16 + lr;
        float bs = bias[ng];
#pragma unroll
        for (int r = 0; r < 4; ++r) {
          int mg = m0 + wr + mi * 16 + g * 4 + r;
          Cf[(size_t)mg * N + ng] = acc[mi][ni][r] + bs;
        }
      }
    }
  } else {
#pragma unroll
    for (int mi = 0; mi < 4; ++mi) {
      int mg0 = m0 + wr + mi * 16 + g * 4;    // t multiple of 4
      int b = mg0 >> 11;                      // /T_SEQ
      int t = mg0 & (T_SEQ - 1);
#pragma unroll
      for (int ni = 0; ni < 4; ++ni) {
        int ng = n0 + wc + ni * 16 + lr;
        float bs = bias[ng];
        int sect = ng >> 10;                  // 0=Q 1=K 2=V (uniform per frag)
        int nm = ng & 1023;
        int h = nm >> 6, d = nm & 63;
        u16 bv[4];
#pragma unroll
        for (int r = 0; r < 4; ++r) bv[r] = f2bf(acc[mi][ni][r] + bs);
        size_t hb = (size_t)b * NHEAD + h;
        if (sect == 0) {
          u16* q = Qb + (hb * T_SEQ + t) * DKH + d;
#pragma unroll
          for (int r = 0; r < 4; ++r) q[(size_t)r * DKH] = bv[r];
        } else if (sect == 1) {
          u16* kk = Kb + (hb * T_SEQ + t) * DKH + d;
#pragma unroll
          for (int r = 0; r < 4; ++r) kk[(size_t)r * DKH] = bv[r];
        } else {
          u16* vp = Vtb + (hb * DKH + d) * T_SEQ + t;  // 8B-aligned (t%4==0)
          ushort4 v4;
          v4.x = bv[0]; v4.y = bv[1]; v4.z = bv[2]; v4.w = bv[3];
          *(ushort4*)vp = v4;
        }
      }
    }
  }
}

// ---------------- flash attention (causal) ----------------
// Block: 4 waves x 32 q-rows = 128-row q tile. KV tiles of 64.
// K tile [64][64] and Vt tile [64(d)][64(kv)] staged linearly via global_load_lds with
// content XOR-swizzle (byte ^= ((row&7)<<4)) applied on the GLOBAL source (m173 pattern),
// un-XOR'd on the ds_read side -> balanced 8 accesses/bank (minimum for 1KB wave read).
__global__ __launch_bounds__(256) void k_attn(const u16* __restrict__ Qb,
                                              const u16* __restrict__ Kb,
                                              const u16* __restrict__ Vtb,
                                              u16* __restrict__ Ob) {
  __shared__ u16 Ks[64 * 64];
  __shared__ u16 Vs[64 * 64];
  __shared__ u16 Ps[4][32 * 72];  // per-wave P buffer, row stride 72 (144B, 16B aligned)
  const int tid = threadIdx.x;
  const int w = tid >> 6, l = tid & 63;
  const int g = l >> 4, lr = l & 15;
  const int bh = blockIdx.y;
  const int b = bh >> 4, h = bh & 15;
  const int qt = (int)(gridDim.x - 1) - (int)blockIdx.x;  // big (causal) tiles first
  const int q0 = qt * 128;
  const int q0w = q0 + w * 32;
  const u16* Qg = Qb + (size_t)bh * T_SEQ * DKH;
  const u16* Kg = Kb + (size_t)bh * T_SEQ * DKH;
  const u16* Vg = Vtb + (size_t)bh * DKH * T_SEQ;

  // Q fragments held in registers for the whole block
  short8 qfr[2][2];
#pragma unroll
  for (int qi = 0; qi < 2; ++qi)
#pragma unroll
    for (int ka = 0; ka < 2; ++ka)
      qfr[qi][ka] = *(const short8*)&Qg[(size_t)(q0w + qi * 16 + lr) * DKH + ka * 32 + g * 8];

  f32x4 o[2][4] = {};
  float m_[2][4], l_[2][4];
#pragma unroll
  for (int qi = 0; qi < 2; ++qi)
#pragma unroll
    for (int r = 0; r < 4; ++r) { m_[qi][r] = -1e30f; l_[qi][r] = 0.f; }

  const int ntile = q0 / 64 + 2;
  for (int kt = 0; kt < ntile; ++kt) {
    const int kv0 = kt * 64;
    // ---- stage K and Vt (content-swizzled) ----
#pragma unroll
    for (int i = 0; i < 2; ++i) {
      int blk = i * 4 + w;
      int x = blk * 1024 + l * 16;                 // LDS byte this lane fills
      int c = x ^ (((x >> 7) & 7) << 4);           // canonical byte it must contain
      int crow = c >> 7;                           // row (kv for K, d for V)
      int ccolb = c & 127;                         // byte-in-row
      async_copy16(&Kg[(size_t)(kv0 + crow) * DKH + (ccolb >> 1)], &Ks[blk * 512]);
      async_copy16(&Vg[(size_t)crow * T_SEQ + kv0 + (ccolb >> 1)], &Vs[blk * 512]);
    }
    __syncthreads();

    if (kv0 <= q0w + 31) {  // wave has unmasked work in this tile
      const bool diag = (kv0 + 63 > q0w);
      // ---- S = Q K^T ----
      short8 kf[4][2];
#pragma unroll
      for (int kv = 0; kv < 4; ++kv)
#pragma unroll
        for (int ka = 0; ka < 2; ++ka) {
          int row = kv * 16 + lr;
          int c = row * 128 + ka * 64 + g * 16;
          int x = c ^ ((row & 7) << 4);
          kf[kv][ka] = *(const short8*)((const char*)Ks + x);
        }
      f32x4 s[2][4] = {};
#pragma unroll
      for (int qi = 0; qi < 2; ++qi)
#pragma unroll
        for (int kv = 0; kv < 4; ++kv)
#pragma unroll
          for (int ka = 0; ka < 2; ++ka)
            s[qi][kv] = __builtin_amdgcn_mfma_f32_16x16x32_bf16(qfr[qi][ka], kf[kv][ka], s[qi][kv], 0, 0, 0);

      // ---- scale + causal mask (in place) ----
#pragma unroll
      for (int qi = 0; qi < 2; ++qi)
#pragma unroll
        for (int kv = 0; kv < 4; ++kv)
#pragma unroll
          for (int r = 0; r < 4; ++r) {
            float sv = s[qi][kv][r] * 0.125f;
            if (diag) {
              int qq = q0w + qi * 16 + g * 4 + r;
              int kk = kv0 + kv * 16 + lr;
              if (kk > qq) sv = -1e30f;
            }
            s[qi][kv][r] = sv;
          }
      // ---- row max (within 16-lane group) ----
      float pm[2][4];
#pragma unroll
      for (int qi = 0; qi < 2; ++qi)
#pragma unroll
        for (int r = 0; r < 4; ++r) {
          float v = fmaxf(fmaxf(s[qi][0][r], s[qi][1][r]), fmaxf(s[qi][2][r], s[qi][3][r]));
          v = fmaxf(v, __shfl_xor(v, 1));
          v = fmaxf(v, __shfl_xor(v, 2));
          v = fmaxf(v, __shfl_xor(v, 4));
          v = fmaxf(v, __shfl_xor(v, 8));
          pm[qi][r] = v;
        }
      // ---- online update: m, alpha, rescale o/l ----
#pragma unroll
      for (int qi = 0; qi < 2; ++qi)
#pragma unroll
        for (int r = 0; r < 4; ++r) {
          float mn = fmaxf(m_[qi][r], pm[qi][r]);
          float al = __expf(m_[qi][r] - mn);
          m_[qi][r] = mn;
          l_[qi][r] *= al;
#pragma unroll
          for (int df = 0; df < 4; ++df) o[qi][df][r] *= al;
        }
      // ---- P = exp(s - m): LDS write + partial row sums ----
      float ps[2][4] = {};
#pragma unroll
      for (int qi = 0; qi < 2; ++qi)
#pragma unroll
        for (int kv = 0; kv < 4; ++kv)
#pragma unroll
          for (int r = 0; r < 4; ++r) {
            float p = __expf(s[qi][kv][r] - m_[qi][r]);
            ps[qi][r] += p;
            Ps[w][(qi * 16 + g * 4 + r) * 72 + kv * 16 + lr] = f2bf(p);
          }
#pragma unroll
      for (int qi = 0; qi < 2; ++qi)
#pragma unroll
        for (int r = 0; r < 4; ++r) {
          float v = ps[qi][r];
          v += __shfl_xor(v, 1);
          v += __shfl_xor(v, 2);
          v += __shfl_xor(v, 4);
          v += __shfl_xor(v, 8);
          l_[qi][r] += v;
        }
      // ---- O += P V ----
      short8 pf[2][2];
#pragma unroll
      for (int qi = 0; qi < 2; ++qi)
#pragma unroll
        for (int ka = 0; ka < 2; ++ka)
          pf[qi][ka] = *(const short8*)&Ps[w][(qi * 16 + lr) * 72 + ka * 32 + g * 8];
      short8 vf[4][2];
#pragma unroll
      for (int df = 0; df < 4; ++df)
#pragma unroll
        for (int ka = 0; ka < 2; ++ka) {
          int row = df * 16 + lr;
          int c = row * 128 + ka * 64 + g * 16;
          int x = c ^ ((row & 7) << 4);
          vf[df][ka] = *(const short8*)((const char*)Vs + x);
        }
#pragma unroll
      for (int qi = 0; qi < 2; ++qi)
#pragma unroll
        for (int df = 0; df < 4; ++df)
#pragma unroll
          for (int ka = 0; ka < 2; ++ka)
            o[qi][df] = __builtin_amdgcn_mfma_f32_16x16x32_bf16(pf[qi][ka], vf[df][ka], o[qi][df], 0, 0, 0);
    }
    __syncthreads();
  }

  // ---- epilogue: Ob[B,T,C] bf16, normalized by row sum ----
#pragma unroll
  for (int qi = 0; qi < 2; ++qi)
#pragma unroll
    for (int r = 0; r < 4; ++r) {
      float inv = 1.0f / l_[qi][r];
      int tq = q0w + qi * 16 + g * 4 + r;
      size_t base = ((size_t)b * T_SEQ + tq) * CEMB + h * 64;
#pragma unroll
      for (int df = 0; df < 4; ++df)
        Ob[base + df * 16 + lr] = f2bf(o[qi][df][r] * inv);
    }
}

// ---------------- launcher ----------------
extern "C" void kernel_launch(void* const* d_in, const int* in_sizes, int n_in,
                              void* d_out, int out_size, void* d_ws, size_t ws_size,
                              hipStream_t stream) {
  const float* x = (const float*)d_in[0];
  const float* Wqkv = (const float*)d_in[1];
  const float* bqkv = (const float*)d_in[2];
  const float* Wout = (const float*)d_in[3];
  const float* bout = (const float*)d_in[4];
  float* out = (float*)d_out;

  char* ws = (char*)d_ws;
  // workspace carve (total ~92.3 MB)
  u16* xb  = (u16*)(ws + 0);           // 16 MB  x bf16 [8192,1024]
  u16* WqT = (u16*)(ws + 16777216);    // 6 MB   Wqkv^T bf16 [3072,1024]
  u16* WoT = (u16*)(ws + 23068672);    // 2 MB   Wout^T bf16 [1024,1024]
  u16* Qb  = (u16*)(ws + 25165824);    // 16 MB  [B,H,T,64]
  u16* Kb  = (u16*)(ws + 41943040);    // 16 MB  [B,H,T,64]
  u16* Vtb = (u16*)(ws + 58720256);    // 16 MB  [B,H,64,T]
  u16* Ob  = (u16*)(ws + 75497472);    // 16 MB  [B,T,C] bf16

  k_convert<<<4096, 256, 0, stream>>>(x, xb, (NBATCH * T_SEQ * CEMB) / 8);
  k_transpose<<<dim3(96, 32), 256, 0, stream>>>(Wqkv, WqT, 1024, 3072);
  k_transpose<<<dim3(32, 32), 256, 0, stream>>>(Wout, WoT, 1024, 1024);
  k_gemm_bt<1><<<dim3(24, 64), 256, 0, stream>>>(xb, WqT, bqkv, nullptr, Qb, Kb, Vtb,
                                                 NBATCH * T_SEQ, 3 * CEMB, CEMB);
  k_attn<<<dim3(16, 64), 256, 0, stream>>>(Qb, Kb, Vtb, Ob);
  k_gemm_bt<0><<<dim3(8, 64), 256, 0, stream>>>(Ob, WoT, bout, out, nullptr, nullptr, nullptr,
                                                NBATCH * T_SEQ, CEMB, CEMB);
}

// Round 4
// 355.521 us; speedup vs baseline: 1.1935x; 1.1935x over previous
//
#include <hip/hip_runtime.h>

// CausalSelfAttention: B=4, T=2048, C=1024, H=16, d_k=64
// Pipeline: convert(x,W)->bf16  |  GEMM1 qkv (+scatter Q,K,Vt)  |  flash attn  |  GEMM2 out
#define T_SEQ 2048
#define NBATCH 4
#define NHEAD 16
#define DKH 64
#define CEMB 1024

typedef unsigned short u16;
typedef __attribute__((ext_vector_type(8))) short short8;
typedef __attribute__((ext_vector_type(8))) unsigned short ushort8v;
typedef __attribute__((ext_vector_type(4))) float f32x4;

__device__ __forceinline__ u16 f2bf(float f) {
  unsigned int x = __builtin_bit_cast(unsigned int, f);
  x += 0x7FFFu + ((x >> 16) & 1u);   // RNE
  return (u16)(x >> 16);
}

__device__ __forceinline__ void async_copy16(const void* g, void* lds) {
  __builtin_amdgcn_global_load_lds(
      (const __attribute__((address_space(1))) void*)g,
      (__attribute__((address_space(3))) void*)lds, 16, 0, 0);
}

// ---------------- convert f32 -> bf16 (8 elems/thread) ----------------
__global__ __launch_bounds__(256) void k_convert(const float* __restrict__ in,
                                                 u16* __restrict__ out, int n8) {
  int i = blockIdx.x * 256 + threadIdx.x;
  if (i >= n8) return;
  const float4* p = (const float4*)in;
  float4 a = p[2 * i], b = p[2 * i + 1];
  ushort8v v;
  v[0] = f2bf(a.x); v[1] = f2bf(a.y); v[2] = f2bf(a.z); v[3] = f2bf(a.w);
  v[4] = f2bf(b.x); v[5] = f2bf(b.y); v[6] = f2bf(b.z); v[7] = f2bf(b.w);
  ((ushort8v*)out)[i] = v;
}

// ---------------- transpose+convert: W[R][C] f32 -> WT[C][R] bf16 ----------------
__global__ __launch_bounds__(256) void k_transpose(const float* __restrict__ W,
                                                   u16* __restrict__ WT, int R, int C) {
  __shared__ float tile[32][33];
  int c0 = blockIdx.x * 32, r0 = blockIdx.y * 32;
  int tx = threadIdx.x & 31;
  int ty = threadIdx.x >> 5;  // 0..7
#pragma unroll
  for (int i = 0; i < 4; ++i) {
    int r = ty + i * 8;
    tile[r][tx] = W[(size_t)(r0 + r) * C + c0 + tx];
  }
  __syncthreads();
#pragma unroll
  for (int i = 0; i < 4; ++i) {
    int cc = ty + i * 8;
    WT[(size_t)(c0 + cc) * R + r0 + tx] = f2bf(tile[tx][cc]);
  }
}

// ---------------- GEMM C = A[M,K] * BT[N,K]^T  (bf16 in, f32 acc) ----------------
// m97 structure: 128x128 tile, BK=32, 4 waves (2x2 of 64x64), 4x4 frags, global_load_lds.
// EPI=0: Cf[M,N] = acc + bias[n]   (f32 out)
// EPI=1: scatter qkv: n<1024 -> Qb[B,H,T,64]; <2048 -> Kb; else Vtb[B,H,64,T] (transposed)
template <int EPI>
__global__ __launch_bounds__(256) void k_gemm_bt(
    const u16* __restrict__ A, const u16* __restrict__ BT, const float* __restrict__ bias,
    float* __restrict__ Cf, u16* __restrict__ Qb, u16* __restrict__ Kb, u16* __restrict__ Vtb,
    int M, int N, int K) {
  __shared__ u16 As[128 * 32];
  __shared__ u16 Bs[128 * 32];
  const int tid = threadIdx.x;
  const int w = tid >> 6, l = tid & 63;
  const int g = l >> 4, lr = l & 15;
  const int m0 = blockIdx.y * 128, n0 = blockIdx.x * 128;
  const int wr = (w >> 1) * 64, wc = (w & 1) * 64;
  f32x4 acc[4][4] = {};

  const int srow = l >> 2;           // 0..15
  const int scol = (l & 3) << 3;     // 0,8,16,24
  const u16* Ag = A + (size_t)m0 * K + scol;
  const u16* Bg = BT + (size_t)n0 * K + scol;

  for (int k0 = 0; k0 < K; k0 += 32) {
#pragma unroll
    for (int i = 0; i < 2; ++i) {
      int blk = i * 4 + w;           // 0..7: 16-row chunk of the tile
      int row = blk * 16 + srow;
      async_copy16(Ag + (size_t)row * K + k0, &As[blk * 512]);
      async_copy16(Bg + (size_t)row * K + k0, &Bs[blk * 512]);
    }
    __syncthreads();
    short8 af[4], bf[4];
#pragma unroll
    for (int mi = 0; mi < 4; ++mi)
      af[mi] = *(const short8*)&As[(wr + mi * 16 + lr) * 32 + g * 8];
#pragma unroll
    for (int ni = 0; ni < 4; ++ni)
      bf[ni] = *(const short8*)&Bs[(wc + ni * 16 + lr) * 32 + g * 8];
#pragma unroll
    for (int mi = 0; mi < 4; ++mi)
#pragma unroll
      for (int ni = 0; ni < 4; ++ni)
        acc[mi][ni] = __builtin_amdgcn_mfma_f32_16x16x32_bf16(af[mi], bf[ni], acc[mi][ni], 0, 0, 0);
    __syncthreads();
  }

  if constexpr (EPI == 0) {
#pragma unroll
    for (int mi = 0; mi < 4; ++mi) {
#pragma unroll
      for (int ni = 0; ni < 4; ++ni) {
        int ng = n0 + wc + ni * 16 + lr;
        float bs = bias[ng];
#pragma unroll
        for (int r = 0; r < 4; ++r) {
          int mg = m0 + wr + mi * 16 + g * 4 + r;
          Cf[(size_t)mg * N + ng] = acc[mi][ni][r] + bs;
        }
      }
    }
  } else {
#pragma unroll
    for (int mi = 0; mi < 4; ++mi) {
      int mg0 = m0 + wr + mi * 16 + g * 4;    // t multiple of 4
      int b = mg0 >> 11;                      // /T_SEQ
      int t = mg0 & (T_SEQ - 1);
#pragma unroll
      for (int ni = 0; ni < 4; ++ni) {
        int ng = n0 + wc + ni * 16 + lr;
        float bs = bias[ng];
        int sect = ng >> 10;                  // 0=Q 1=K 2=V (uniform per frag)
        int nm = ng & 1023;
        int h = nm >> 6, d = nm & 63;
        u16 bv[4];
#pragma unroll
        for (int r = 0; r < 4; ++r) bv[r] = f2bf(acc[mi][ni][r] + bs);
        size_t hb = (size_t)b * NHEAD + h;
        if (sect == 0) {
          u16* q = Qb + (hb * T_SEQ + t) * DKH + d;
#pragma unroll
          for (int r = 0; r < 4; ++r) q[(size_t)r * DKH] = bv[r];
        } else if (sect == 1) {
          u16* kk = Kb + (hb * T_SEQ + t) * DKH + d;
#pragma unroll
          for (int r = 0; r < 4; ++r) kk[(size_t)r * DKH] = bv[r];
        } else {
          u16* vp = Vtb + (hb * DKH + d) * T_SEQ + t;  // 8B-aligned (t%4==0)
          ushort4 v4;
          v4.x = bv[0]; v4.y = bv[1]; v4.z = bv[2]; v4.w = bv[3];
          *(ushort4*)vp = v4;
        }
      }
    }
  }
}

// ---------------- flash attention (causal), 2-phase pipelined ----------------
// 4 waves x 32 q-rows = 128-row q tile, KVB=64. Double-buffered K/Vt staging:
// per tile: STAGE(next buf) -> compute(cur buf) -> __syncthreads().
// __syncthreads (NOT raw s_barrier: its fence semantics keep the compiler from
// hoisting ds_reads / sinking STAGE across the barrier — raw version raced, R3).
// Stage latency hides under compute. Content XOR-swizzle (byte ^= ((row&7)<<4))
// pre-applied on the global source, un-XOR'd on ds_read.
// Softmax: defer-max (skip cross-lane max + rescale unless local max > m+64 raw,
// i.e. 8 in scaled space); per-lane partial row-sums reduced once at epilogue.
__global__ __launch_bounds__(256) void k_attn(const u16* __restrict__ Qb,
                                              const u16* __restrict__ Kb,
                                              const u16* __restrict__ Vtb,
                                              u16* __restrict__ Ob) {
  __shared__ u16 Ks[2][64 * 64];
  __shared__ u16 Vs[2][64 * 64];
  __shared__ u16 Ps[4][32 * 72];  // per-wave P buffer, row stride 72 (144B, 16B aligned)
  const int tid = threadIdx.x;
  const int w = tid >> 6, l = tid & 63;
  const int g = l >> 4, lr = l & 15;
  const int bh = blockIdx.y;
  const int b = bh >> 4, h = bh & 15;
  const int qt = (int)(gridDim.x - 1) - (int)blockIdx.x;  // big (causal) tiles first
  const int q0 = qt * 128;
  const int q0w = q0 + w * 32;
  const u16* Qg = Qb + (size_t)bh * T_SEQ * DKH;
  const u16* Kg = Kb + (size_t)bh * T_SEQ * DKH;
  const u16* Vg = Vtb + (size_t)bh * DKH * T_SEQ;

  // per-lane swizzled staging source bases (hoisted out of the tile loop)
  const u16* KgL[2];
  const u16* VgL[2];
  int blkArr[2];
#pragma unroll
  for (int i = 0; i < 2; ++i) {
    int blk = i * 4 + w;
    blkArr[i] = blk;
    int x = blk * 1024 + l * 16;            // LDS byte this lane fills
    int c = x ^ (((x >> 7) & 7) << 4);      // canonical byte it must contain
    int crow = c >> 7;
    int ccolb = c & 127;
    KgL[i] = Kg + crow * DKH + (ccolb >> 1);
    VgL[i] = Vg + (size_t)crow * T_SEQ + (ccolb >> 1);
  }

  auto STAGE = [&](int bufi, int kv0) {
#pragma unroll
    for (int i = 0; i < 2; ++i) {
      async_copy16(KgL[i] + (size_t)kv0 * DKH, &Ks[bufi][blkArr[i] * 512]);
      async_copy16(VgL[i] + kv0, &Vs[bufi][blkArr[i] * 512]);
    }
  };

  STAGE(0, 0);

  // Q fragments held in registers for the whole block
  short8 qfr[2][2];
#pragma unroll
  for (int qi = 0; qi < 2; ++qi)
#pragma unroll
    for (int ka = 0; ka < 2; ++ka)
      qfr[qi][ka] = *(const short8*)&Qg[(size_t)(q0w + qi * 16 + lr) * DKH + ka * 32 + g * 8];

  f32x4 o[2][4] = {};
  float m_[2][4], lp[2][4];
#pragma unroll
  for (int qi = 0; qi < 2; ++qi)
#pragma unroll
    for (int r = 0; r < 4; ++r) { m_[qi][r] = -1e30f; lp[qi][r] = 0.f; }

  __syncthreads();

  const int ntile = q0 / 64 + 2;
  for (int kt = 0; kt < ntile; ++kt) {
    const int cur = kt & 1;
    const int kv0 = kt * 64;
    if (kt + 1 < ntile) STAGE(cur ^ 1, kv0 + 64);  // prefetch next tile

    if (kv0 <= q0w) {  // wave has unmasked work in this tile
      const bool diag = (kv0 + 63 > q0w);
      const char* KsB = (const char*)Ks[cur];
      const char* VsB = (const char*)Vs[cur];
      // ---- S = Q K^T (raw, unscaled) ----
      short8 kf[4][2];
#pragma unroll
      for (int kv = 0; kv < 4; ++kv)
#pragma unroll
        for (int ka = 0; ka < 2; ++ka) {
          int row = kv * 16 + lr;
          int cidx = row * 128 + ka * 64 + g * 16;
          int x = cidx ^ ((row & 7) << 4);
          kf[kv][ka] = *(const short8*)(KsB + x);
        }
      f32x4 s[2][4] = {};
      __builtin_amdgcn_s_setprio(1);
#pragma unroll
      for (int qi = 0; qi < 2; ++qi)
#pragma unroll
        for (int kv = 0; kv < 4; ++kv)
#pragma unroll
          for (int ka = 0; ka < 2; ++ka)
            s[qi][kv] = __builtin_amdgcn_mfma_f32_16x16x32_bf16(qfr[qi][ka], kf[kv][ka], s[qi][kv], 0, 0, 0);
      __builtin_amdgcn_s_setprio(0);

      // ---- causal mask on raw scores ----
      if (diag) {
#pragma unroll
        for (int qi = 0; qi < 2; ++qi)
#pragma unroll
          for (int kv = 0; kv < 4; ++kv)
#pragma unroll
            for (int r = 0; r < 4; ++r) {
              int qq = q0w + qi * 16 + g * 4 + r;
              int kk = kv0 + kv * 16 + lr;
              if (kk > qq) s[qi][kv][r] = -1e30f;
            }
      }

      // ---- defer-max: per-lane local max, update only when it grows past m+64 ----
      float pmx[2][4];
      bool grow = false;
#pragma unroll
      for (int qi = 0; qi < 2; ++qi)
#pragma unroll
        for (int r = 0; r < 4; ++r) {
          float v = fmaxf(fmaxf(s[qi][0][r], s[qi][1][r]), fmaxf(s[qi][2][r], s[qi][3][r]));
          pmx[qi][r] = v;
          grow = grow || (v > m_[qi][r] + 64.f);  // 64 raw = 8 in scaled space
        }
      if (__any(grow)) {
#pragma unroll
        for (int qi = 0; qi < 2; ++qi)
#pragma unroll
          for (int r = 0; r < 4; ++r) {
            float v = pmx[qi][r];
            v = fmaxf(v, __shfl_xor(v, 1));
            v = fmaxf(v, __shfl_xor(v, 2));
            v = fmaxf(v, __shfl_xor(v, 4));
            v = fmaxf(v, __shfl_xor(v, 8));
            float mn = fmaxf(m_[qi][r], v);
            float al = __expf((m_[qi][r] - mn) * 0.125f);
            m_[qi][r] = mn;
            lp[qi][r] *= al;
#pragma unroll
            for (int df = 0; df < 4; ++df) o[qi][df][r] *= al;
          }
      }

      // ---- P = exp((s-m)*scale): bf16 LDS write + per-lane partial sums ----
#pragma unroll
      for (int qi = 0; qi < 2; ++qi)
#pragma unroll
        for (int r = 0; r < 4; ++r) {
          float mm = m_[qi][r];
          float p0 = __expf((s[qi][0][r] - mm) * 0.125f);
          float p1 = __expf((s[qi][1][r] - mm) * 0.125f);
          float p2 = __expf((s[qi][2][r] - mm) * 0.125f);
          float p3 = __expf((s[qi][3][r] - mm) * 0.125f);
          lp[qi][r] += (p0 + p1) + (p2 + p3);
          u16* base = &Ps[w][(qi * 16 + g * 4 + r) * 72 + lr];
          base[0]  = f2bf(p0);
          base[16] = f2bf(p1);
          base[32] = f2bf(p2);
          base[48] = f2bf(p3);
        }

      // ---- O += P V ----
      short8 pf[2][2];
#pragma unroll
      for (int qi = 0; qi < 2; ++qi)
#pragma unroll
        for (int ka = 0; ka < 2; ++ka)
          pf[qi][ka] = *(const short8*)&Ps[w][(qi * 16 + lr) * 72 + ka * 32 + g * 8];
      short8 vf[4][2];
#pragma unroll
      for (int df = 0; df < 4; ++df)
#pragma unroll
        for (int ka = 0; ka < 2; ++ka) {
          int row = df * 16 + lr;
          int cidx = row * 128 + ka * 64 + g * 16;
          int x = cidx ^ ((row & 7) << 4);
          vf[df][ka] = *(const short8*)(VsB + x);
        }
      __builtin_amdgcn_s_setprio(1);
#pragma unroll
      for (int qi = 0; qi < 2; ++qi)
#pragma unroll
        for (int df = 0; df < 4; ++df)
#pragma unroll
          for (int ka = 0; ka < 2; ++ka)
            o[qi][df] = __builtin_amdgcn_mfma_f32_16x16x32_bf16(pf[qi][ka], vf[df][ka], o[qi][df], 0, 0, 0);
      __builtin_amdgcn_s_setprio(0);
    }

    // per-tile sync: fence semantics (vmcnt drain is cheap — prefetch had the whole
    // compute phase to land) and keeps compiler from moving LDS ops across.
    __syncthreads();
  }

  // ---- epilogue: reduce per-lane partial sums, write Ob[B,T,C] bf16 ----
#pragma unroll
  for (int qi = 0; qi < 2; ++qi)
#pragma unroll
    for (int r = 0; r < 4; ++r) {
      float v = lp[qi][r];
      v += __shfl_xor(v, 1);
      v += __shfl_xor(v, 2);
      v += __shfl_xor(v, 4);
      v += __shfl_xor(v, 8);
      float inv = 1.0f / v;
      int tq = q0w + qi * 16 + g * 4 + r;
      size_t base = ((size_t)b * T_SEQ + tq) * CEMB + h * 64;
#pragma unroll
      for (int df = 0; df < 4; ++df)
        Ob[base + df * 16 + lr] = f2bf(o[qi][df][r] * inv);
    }
}

// ---------------- launcher ----------------
extern "C" void kernel_launch(void* const* d_in, const int* in_sizes, int n_in,
                              void* d_out, int out_size, void* d_ws, size_t ws_size,
                              hipStream_t stream) {
  const float* x = (const float*)d_in[0];
  const float* Wqkv = (const float*)d_in[1];
  const float* bqkv = (const float*)d_in[2];
  const float* Wout = (const float*)d_in[3];
  const float* bout = (const float*)d_in[4];
  float* out = (float*)d_out;

  char* ws = (char*)d_ws;
  // workspace carve (total ~92.3 MB)
  u16* xb  = (u16*)(ws + 0);           // 16 MB  x bf16 [8192,1024]
  u16* WqT = (u16*)(ws + 16777216);    // 6 MB   Wqkv^T bf16 [3072,1024]
  u16* WoT = (u16*)(ws + 23068672);    // 2 MB   Wout^T bf16 [1024,1024]
  u16* Qb  = (u16*)(ws + 25165824);    // 16 MB  [B,H,T,64]
  u16* Kb  = (u16*)(ws + 41943040);    // 16 MB  [B,H,T,64]
  u16* Vtb = (u16*)(ws + 58720256);    // 16 MB  [B,H,64,T]
  u16* Ob  = (u16*)(ws + 75497472);    // 16 MB  [B,T,C] bf16

  k_convert<<<4096, 256, 0, stream>>>(x, xb, (NBATCH * T_SEQ * CEMB) / 8);
  k_transpose<<<dim3(96, 32), 256, 0, stream>>>(Wqkv, WqT, 1024, 3072);
  k_transpose<<<dim3(32, 32), 256, 0, stream>>>(Wout, WoT, 1024, 1024);
  k_gemm_bt<1><<<dim3(24, 64), 256, 0, stream>>>(xb, WqT, bqkv, nullptr, Qb, Kb, Vtb,
                                                 NBATCH * T_SEQ, 3 * CEMB, CEMB);
  k_attn<<<dim3(16, 64), 256, 0, stream>>>(Qb, Kb, Vtb, Ob);
  k_gemm_bt<0><<<dim3(8, 64), 256, 0, stream>>>(Ob, WoT, bout, out, nullptr, nullptr, nullptr,
                                                NBATCH * T_SEQ, CEMB, CEMB);
}

// Round 5
// 294.064 us; speedup vs baseline: 1.4429x; 1.2090x over previous
//
#include <hip/hip_runtime.h>

// CausalSelfAttention: B=4, T=2048, C=1024, H=16, d_k=64
// Pipeline: convert(x,W)->bf16  |  GEMM1 qkv (+scatter Q,K,Vt)  |  flash attn  |  GEMM2 out
#define T_SEQ 2048
#define NBATCH 4
#define NHEAD 16
#define DKH 64
#define CEMB 1024

typedef unsigned short u16;
typedef __attribute__((ext_vector_type(8))) short short8;
typedef __attribute__((ext_vector_type(8))) unsigned short ushort8v;
typedef __attribute__((ext_vector_type(4))) float f32x4;

__device__ __forceinline__ u16 f2bf(float f) {
  unsigned int x = __builtin_bit_cast(unsigned int, f);
  x += 0x7FFFu + ((x >> 16) & 1u);   // RNE
  return (u16)(x >> 16);
}

__device__ __forceinline__ void async_copy16(const void* g, void* lds) {
  __builtin_amdgcn_global_load_lds(
      (const __attribute__((address_space(1))) void*)g,
      (__attribute__((address_space(3))) void*)lds, 16, 0, 0);
}

// ---------------- convert f32 -> bf16 (8 elems/thread) ----------------
__global__ __launch_bounds__(256) void k_convert(const float* __restrict__ in,
                                                 u16* __restrict__ out, int n8) {
  int i = blockIdx.x * 256 + threadIdx.x;
  if (i >= n8) return;
  const float4* p = (const float4*)in;
  float4 a = p[2 * i], b = p[2 * i + 1];
  ushort8v v;
  v[0] = f2bf(a.x); v[1] = f2bf(a.y); v[2] = f2bf(a.z); v[3] = f2bf(a.w);
  v[4] = f2bf(b.x); v[5] = f2bf(b.y); v[6] = f2bf(b.z); v[7] = f2bf(b.w);
  ((ushort8v*)out)[i] = v;
}

// ---------------- transpose+convert: W[R][C] f32 -> WT[C][R] bf16 ----------------
__global__ __launch_bounds__(256) void k_transpose(const float* __restrict__ W,
                                                   u16* __restrict__ WT, int R, int C) {
  __shared__ float tile[32][33];
  int c0 = blockIdx.x * 32, r0 = blockIdx.y * 32;
  int tx = threadIdx.x & 31;
  int ty = threadIdx.x >> 5;  // 0..7
#pragma unroll
  for (int i = 0; i < 4; ++i) {
    int r = ty + i * 8;
    tile[r][tx] = W[(size_t)(r0 + r) * C + c0 + tx];
  }
  __syncthreads();
#pragma unroll
  for (int i = 0; i < 4; ++i) {
    int cc = ty + i * 8;
    WT[(size_t)(c0 + cc) * R + r0 + tx] = f2bf(tile[tx][cc]);
  }
}

// ---------------- GEMM C = A[M,K] * BT[N,K]^T  (bf16 in, f32 acc) ----------------
// m97 structure: 128x128 tile, BK=32, 4 waves (2x2 of 64x64), 4x4 frags, global_load_lds.
// EPI=0: Cf[M,N] = acc + bias[n]   (f32 out)
// EPI=1: scatter qkv: n<1024 -> Qb[B,H,T,64]; <2048 -> Kb; else Vtb[B,H,64,T] (transposed)
template <int EPI>
__global__ __launch_bounds__(256) void k_gemm_bt(
    const u16* __restrict__ A, const u16* __restrict__ BT, const float* __restrict__ bias,
    float* __restrict__ Cf, u16* __restrict__ Qb, u16* __restrict__ Kb, u16* __restrict__ Vtb,
    int M, int N, int K) {
  __shared__ u16 As[128 * 32];
  __shared__ u16 Bs[128 * 32];
  const int tid = threadIdx.x;
  const int w = tid >> 6, l = tid & 63;
  const int g = l >> 4, lr = l & 15;
  const int m0 = blockIdx.y * 128, n0 = blockIdx.x * 128;
  const int wr = (w >> 1) * 64, wc = (w & 1) * 64;
  f32x4 acc[4][4] = {};

  const int srow = l >> 2;           // 0..15
  const int scol = (l & 3) << 3;     // 0,8,16,24
  const u16* Ag = A + (size_t)m0 * K + scol;
  const u16* Bg = BT + (size_t)n0 * K + scol;

  for (int k0 = 0; k0 < K; k0 += 32) {
#pragma unroll
    for (int i = 0; i < 2; ++i) {
      int blk = i * 4 + w;           // 0..7: 16-row chunk of the tile
      int row = blk * 16 + srow;
      async_copy16(Ag + (size_t)row * K + k0, &As[blk * 512]);
      async_copy16(Bg + (size_t)row * K + k0, &Bs[blk * 512]);
    }
    __syncthreads();
    short8 af[4], bf[4];
#pragma unroll
    for (int mi = 0; mi < 4; ++mi)
      af[mi] = *(const short8*)&As[(wr + mi * 16 + lr) * 32 + g * 8];
#pragma unroll
    for (int ni = 0; ni < 4; ++ni)
      bf[ni] = *(const short8*)&Bs[(wc + ni * 16 + lr) * 32 + g * 8];
#pragma unroll
    for (int mi = 0; mi < 4; ++mi)
#pragma unroll
      for (int ni = 0; ni < 4; ++ni)
        acc[mi][ni] = __builtin_amdgcn_mfma_f32_16x16x32_bf16(af[mi], bf[ni], acc[mi][ni], 0, 0, 0);
    __syncthreads();
  }

  if constexpr (EPI == 0) {
#pragma unroll
    for (int mi = 0; mi < 4; ++mi) {
#pragma unroll
      for (int ni = 0; ni < 4; ++ni) {
        int ng = n0 + wc + ni * 16 + lr;
        float bs = bias[ng];
#pragma unroll
        for (int r = 0; r < 4; ++r) {
          int mg = m0 + wr + mi * 16 + g * 4 + r;
          Cf[(size_t)mg * N + ng] = acc[mi][ni][r] + bs;
        }
      }
    }
  } else {
#pragma unroll
    for (int mi = 0; mi < 4; ++mi) {
      int mg0 = m0 + wr + mi * 16 + g * 4;    // t multiple of 4
      int b = mg0 >> 11;                      // /T_SEQ
      int t = mg0 & (T_SEQ - 1);
#pragma unroll
      for (int ni = 0; ni < 4; ++ni) {
        int ng = n0 + wc + ni * 16 + lr;
        float bs = bias[ng];
        int sect = ng >> 10;                  // 0=Q 1=K 2=V (uniform per frag)
        int nm = ng & 1023;
        int h = nm >> 6, d = nm & 63;
        u16 bv[4];
#pragma unroll
        for (int r = 0; r < 4; ++r) bv[r] = f2bf(acc[mi][ni][r] + bs);
        size_t hb = (size_t)b * NHEAD + h;
        if (sect == 0) {
          u16* q = Qb + (hb * T_SEQ + t) * DKH + d;
#pragma unroll
          for (int r = 0; r < 4; ++r) q[(size_t)r * DKH] = bv[r];
        } else if (sect == 1) {
          u16* kk = Kb + (hb * T_SEQ + t) * DKH + d;
#pragma unroll
          for (int r = 0; r < 4; ++r) kk[(size_t)r * DKH] = bv[r];
        } else {
          u16* vp = Vtb + (hb * DKH + d) * T_SEQ + t;  // 8B-aligned (t%4==0)
          ushort4 v4;
          v4.x = bv[0]; v4.y = bv[1]; v4.z = bv[2]; v4.w = bv[3];
          *(ushort4*)vp = v4;
        }
      }
    }
  }
}

// ---------------- flash attention (causal), paired q-tiles, 2-phase pipelined ----------------
// Load-balance fix: each block owns q-tiles {j, 15-j} (grid 8x64 = 512 blocks, uniform
// 34 kv-tile-computes each, exactly 2 blocks/CU -> no causal tail). K/V staging and
// kf/vf fragment ds_reads are SHARED by both q-tiles. Double-buffered staging,
// one __syncthreads per kv tile (fence semantics required — raw s_barrier raced, R3).
// Content XOR-swizzle (byte ^= ((row&7)<<4)) pre-applied on global source.
// Softmax: defer-max (threshold 64 raw = 8 scaled); per-lane partial sums reduced at epilogue.
__global__ __launch_bounds__(256, 2) void k_attn(const u16* __restrict__ Qb,
                                                 const u16* __restrict__ Kb,
                                                 const u16* __restrict__ Vtb,
                                                 u16* __restrict__ Ob) {
  __shared__ u16 Ks[2][64 * 64];
  __shared__ u16 Vs[2][64 * 64];
  __shared__ u16 Ps[4][32 * 72];  // per-wave P buffer, row stride 72 (144B, 16B aligned)
  const int tid = threadIdx.x;
  const int w = tid >> 6, l = tid & 63;
  const int g = l >> 4, lr = l & 15;
  const int bh = blockIdx.y;
  const int b = bh >> 4, h = bh & 15;
  const int j = blockIdx.x;                 // pair index 0..7
  const int qtB = 15 - j;                   // heavy tile
  const int q0a = j * 128 + w * 32;         // light q-tile rows (this wave)
  const int q0b = qtB * 128 + w * 32;       // heavy q-tile rows (this wave)
  const u16* Qg = Qb + (size_t)bh * T_SEQ * DKH;
  const u16* Kg = Kb + (size_t)bh * T_SEQ * DKH;
  const u16* Vg = Vtb + (size_t)bh * DKH * T_SEQ;

  // per-lane swizzled staging source bases (hoisted out of the tile loop)
  const u16* KgL[2];
  const u16* VgL[2];
  int blkArr[2];
#pragma unroll
  for (int i = 0; i < 2; ++i) {
    int blk = i * 4 + w;
    blkArr[i] = blk;
    int x = blk * 1024 + l * 16;            // LDS byte this lane fills
    int c = x ^ (((x >> 7) & 7) << 4);      // canonical byte it must contain
    int crow = c >> 7;
    int ccolb = c & 127;
    KgL[i] = Kg + crow * DKH + (ccolb >> 1);
    VgL[i] = Vg + (size_t)crow * T_SEQ + (ccolb >> 1);
  }

  auto STAGE = [&](int bufi, int kv0) {
#pragma unroll
    for (int i = 0; i < 2; ++i) {
      async_copy16(KgL[i] + (size_t)kv0 * DKH, &Ks[bufi][blkArr[i] * 512]);
      async_copy16(VgL[i] + kv0, &Vs[bufi][blkArr[i] * 512]);
    }
  };

  STAGE(0, 0);

  // Q fragments for both q-tiles, held in registers for the whole block
  short8 qfrA[2][2], qfrB[2][2];
#pragma unroll
  for (int qi = 0; qi < 2; ++qi)
#pragma unroll
    for (int ka = 0; ka < 2; ++ka) {
      qfrA[qi][ka] = *(const short8*)&Qg[(size_t)(q0a + qi * 16 + lr) * DKH + ka * 32 + g * 8];
      qfrB[qi][ka] = *(const short8*)&Qg[(size_t)(q0b + qi * 16 + lr) * DKH + ka * 32 + g * 8];
    }

  f32x4 oA[2][4] = {}, oB[2][4] = {};
  float mA[2][4], lpA[2][4], mB[2][4], lpB[2][4];
#pragma unroll
  for (int qi = 0; qi < 2; ++qi)
#pragma unroll
    for (int r = 0; r < 4; ++r) {
      mA[qi][r] = -1e30f; lpA[qi][r] = 0.f;
      mB[qi][r] = -1e30f; lpB[qi][r] = 0.f;
    }

  __syncthreads();

  // one q-tile's full compute for the current kv tile (kf/vf preloaded, shared)
  short8 kf[4][2], vf[4][2];
  auto tile_compute = [&](int q0w_, auto& qfr_, auto& o_, auto& m__, auto& lp_, int kv0) {
    const bool diag = (kv0 + 63 > q0w_);
    f32x4 s[2][4] = {};
    __builtin_amdgcn_s_setprio(1);
#pragma unroll
    for (int qi = 0; qi < 2; ++qi)
#pragma unroll
      for (int kv = 0; kv < 4; ++kv)
#pragma unroll
        for (int ka = 0; ka < 2; ++ka)
          s[qi][kv] = __builtin_amdgcn_mfma_f32_16x16x32_bf16(qfr_[qi][ka], kf[kv][ka], s[qi][kv], 0, 0, 0);
    __builtin_amdgcn_s_setprio(0);

    if (diag) {
#pragma unroll
      for (int qi = 0; qi < 2; ++qi)
#pragma unroll
        for (int kv = 0; kv < 4; ++kv)
#pragma unroll
          for (int r = 0; r < 4; ++r) {
            int qq = q0w_ + qi * 16 + g * 4 + r;
            int kk = kv0 + kv * 16 + lr;
            if (kk > qq) s[qi][kv][r] = -1e30f;
          }
    }

    // defer-max: skip cross-lane max + rescale unless local max grows past m+64 (raw)
    float pmx[2][4];
    bool grow = false;
#pragma unroll
    for (int qi = 0; qi < 2; ++qi)
#pragma unroll
      for (int r = 0; r < 4; ++r) {
        float v = fmaxf(fmaxf(s[qi][0][r], s[qi][1][r]), fmaxf(s[qi][2][r], s[qi][3][r]));
        pmx[qi][r] = v;
        grow = grow || (v > m__[qi][r] + 64.f);
      }
    if (__any(grow)) {
#pragma unroll
      for (int qi = 0; qi < 2; ++qi)
#pragma unroll
        for (int r = 0; r < 4; ++r) {
          float v = pmx[qi][r];
          v = fmaxf(v, __shfl_xor(v, 1));
          v = fmaxf(v, __shfl_xor(v, 2));
          v = fmaxf(v, __shfl_xor(v, 4));
          v = fmaxf(v, __shfl_xor(v, 8));
          float mn = fmaxf(m__[qi][r], v);
          float al = __expf((m__[qi][r] - mn) * 0.125f);
          m__[qi][r] = mn;
          lp_[qi][r] *= al;
#pragma unroll
          for (int df = 0; df < 4; ++df) o_[qi][df][r] *= al;
        }
    }

    // P = exp((s-m)*scale): bf16 LDS write + per-lane partial sums
#pragma unroll
    for (int qi = 0; qi < 2; ++qi)
#pragma unroll
      for (int r = 0; r < 4; ++r) {
        float mm = m__[qi][r];
        float p0 = __expf((s[qi][0][r] - mm) * 0.125f);
        float p1 = __expf((s[qi][1][r] - mm) * 0.125f);
        float p2 = __expf((s[qi][2][r] - mm) * 0.125f);
        float p3 = __expf((s[qi][3][r] - mm) * 0.125f);
        lp_[qi][r] += (p0 + p1) + (p2 + p3);
        u16* base = &Ps[w][(qi * 16 + g * 4 + r) * 72 + lr];
        base[0]  = f2bf(p0);
        base[16] = f2bf(p1);
        base[32] = f2bf(p2);
        base[48] = f2bf(p3);
      }

    // O += P V  (same-wave LDS write->read is in-order; Ps reuse across calls is safe)
    short8 pf[2][2];
#pragma unroll
    for (int qi = 0; qi < 2; ++qi)
#pragma unroll
      for (int ka = 0; ka < 2; ++ka)
        pf[qi][ka] = *(const short8*)&Ps[w][(qi * 16 + lr) * 72 + ka * 32 + g * 8];
    __builtin_amdgcn_s_setprio(1);
#pragma unroll
    for (int qi = 0; qi < 2; ++qi)
#pragma unroll
      for (int df = 0; df < 4; ++df)
#pragma unroll
        for (int ka = 0; ka < 2; ++ka)
          o_[qi][df] = __builtin_amdgcn_mfma_f32_16x16x32_bf16(pf[qi][ka], vf[df][ka], o_[qi][df], 0, 0, 0);
    __builtin_amdgcn_s_setprio(0);
  };

  const int ntile = 2 * qtB + 2;  // heavy tile's requirement bounds the loop
  for (int kt = 0; kt < ntile; ++kt) {
    const int cur = kt & 1;
    const int kv0 = kt * 64;
    if (kt + 1 < ntile) STAGE(cur ^ 1, kv0 + 64);  // prefetch next kv tile

    const bool actA = (kv0 <= q0a);
    const bool actB = (kv0 <= q0b);
    if (actB) {  // actA implies actB
      const char* KsB = (const char*)Ks[cur];
      const char* VsB = (const char*)Vs[cur];
#pragma unroll
      for (int kv = 0; kv < 4; ++kv)
#pragma unroll
        for (int ka = 0; ka < 2; ++ka) {
          int row = kv * 16 + lr;
          int cidx = row * 128 + ka * 64 + g * 16;
          int x = cidx ^ ((row & 7) << 4);
          kf[kv][ka] = *(const short8*)(KsB + x);
          vf[kv][ka] = *(const short8*)(VsB + x);
        }
      if (actA) tile_compute(q0a, qfrA, oA, mA, lpA, kv0);
      tile_compute(q0b, qfrB, oB, mB, lpB, kv0);
    }

    __syncthreads();  // fence; prefetch had the whole compute phase to land
  }

  // ---- epilogue: reduce per-lane partial sums, write Ob[B,T,C] bf16 (both q-tiles) ----
#pragma unroll
  for (int qi = 0; qi < 2; ++qi)
#pragma unroll
    for (int r = 0; r < 4; ++r) {
      float va = lpA[qi][r];
      va += __shfl_xor(va, 1); va += __shfl_xor(va, 2);
      va += __shfl_xor(va, 4); va += __shfl_xor(va, 8);
      float inva = 1.0f / va;
      int tqa = q0a + qi * 16 + g * 4 + r;
      size_t basea = ((size_t)b * T_SEQ + tqa) * CEMB + h * 64;
#pragma unroll
      for (int df = 0; df < 4; ++df)
        Ob[basea + df * 16 + lr] = f2bf(oA[qi][df][r] * inva);

      float vb = lpB[qi][r];
      vb += __shfl_xor(vb, 1); vb += __shfl_xor(vb, 2);
      vb += __shfl_xor(vb, 4); vb += __shfl_xor(vb, 8);
      float invb = 1.0f / vb;
      int tqb = q0b + qi * 16 + g * 4 + r;
      size_t baseb = ((size_t)b * T_SEQ + tqb) * CEMB + h * 64;
#pragma unroll
      for (int df = 0; df < 4; ++df)
        Ob[baseb + df * 16 + lr] = f2bf(oB[qi][df][r] * invb);
    }
}

// ---------------- launcher ----------------
extern "C" void kernel_launch(void* const* d_in, const int* in_sizes, int n_in,
                              void* d_out, int out_size, void* d_ws, size_t ws_size,
                              hipStream_t stream) {
  const float* x = (const float*)d_in[0];
  const float* Wqkv = (const float*)d_in[1];
  const float* bqkv = (const float*)d_in[2];
  const float* Wout = (const float*)d_in[3];
  const float* bout = (const float*)d_in[4];
  float* out = (float*)d_out;

  char* ws = (char*)d_ws;
  // workspace carve (total ~92.3 MB)
  u16* xb  = (u16*)(ws + 0);           // 16 MB  x bf16 [8192,1024]
  u16* WqT = (u16*)(ws + 16777216);    // 6 MB   Wqkv^T bf16 [3072,1024]
  u16* WoT = (u16*)(ws + 23068672);    // 2 MB   Wout^T bf16 [1024,1024]
  u16* Qb  = (u16*)(ws + 25165824);    // 16 MB  [B,H,T,64]
  u16* Kb  = (u16*)(ws + 41943040);    // 16 MB  [B,H,T,64]
  u16* Vtb = (u16*)(ws + 58720256);    // 16 MB  [B,H,64,T]
  u16* Ob  = (u16*)(ws + 75497472);    // 16 MB  [B,T,C] bf16

  k_convert<<<4096, 256, 0, stream>>>(x, xb, (NBATCH * T_SEQ * CEMB) / 8);
  k_transpose<<<dim3(96, 32), 256, 0, stream>>>(Wqkv, WqT, 1024, 3072);
  k_transpose<<<dim3(32, 32), 256, 0, stream>>>(Wout, WoT, 1024, 1024);
  k_gemm_bt<1><<<dim3(24, 64), 256, 0, stream>>>(xb, WqT, bqkv, nullptr, Qb, Kb, Vtb,
                                                 NBATCH * T_SEQ, 3 * CEMB, CEMB);
  k_attn<<<dim3(8, 64), 256, 0, stream>>>(Qb, Kb, Vtb, Ob);
  k_gemm_bt<0><<<dim3(8, 64), 256, 0, stream>>>(Ob, WoT, bout, out, nullptr, nullptr, nullptr,
                                                NBATCH * T_SEQ, CEMB, CEMB);
}